// Round 21
// baseline (263.680 us; speedup 1.0000x reference)
//
#include <hip/hip_runtime.h>
#include <hip/hip_bf16.h>
#include <cstddef>

// Problem dims
#define H   512
#define E   256
#define V   32000
#define L   1024
#define B   64
#define KX  768      // E + H
#define G2  2048     // 4*H
#define M_TOT 65536  // L*B

typedef __attribute__((ext_vector_type(8))) _Float16 half8v;
typedef __attribute__((ext_vector_type(4))) float f32x4;

__device__ __forceinline__ half8v cvt8(float4 x0, float4 x1) {
    union { half8v v; _Float16 u[8]; } hv;
    hv.u[0] = (_Float16)x0.x; hv.u[1] = (_Float16)x0.y;
    hv.u[2] = (_Float16)x0.z; hv.u[3] = (_Float16)x0.w;
    hv.u[4] = (_Float16)x1.x; hv.u[5] = (_Float16)x1.y;
    hv.u[6] = (_Float16)x1.z; hv.u[7] = (_Float16)x1.w;
    return hv.v;
}

// async global->LDS, 16B per lane; LDS dst = wave-uniform base + lane*16.
__device__ __forceinline__ void glds16(const void* g, void* l) {
    __builtin_amdgcn_global_load_lds(
        (const __attribute__((address_space(1))) void*)g,
        (__attribute__((address_space(3))) void*)l, 16, 0, 0);
}

// ---------------------------------------------------------------------------
// K-prep: blocks 0..127 -> W_attn[:,H:] into fragment-ordered fp16 WfB;
//         blocks 128..447 -> build xprev_rm (b-major [b][1280]).
// ---------------------------------------------------------------------------
__global__ __launch_bounds__(256) void k_prep(const float* __restrict__ W_attn,
                                              unsigned short* __restrict__ WfB,
                                              const int* __restrict__ inp,
                                              const float* __restrict__ loc,
                                              const float* __restrict__ hprev,
                                              const float* __restrict__ emb,
                                              float* __restrict__ xprev_rm) {
    if (blockIdx.x < 128) {
        int u = blockIdx.x * 256 + threadIdx.x;   // 0..32767 chunks
        int lane = u & 63;
        int rest = u >> 6;                        // (jt*16+kt)*8 + f
        int f = rest & 7;
        int kt = (rest >> 3) & 15;
        int jt = rest >> 7;
        int wn = f >> 2, nf = f & 3;
        int j = jt * 128 + wn * 64 + nf * 16 + (lane & 15);
        int col = kt * 32 + (lane >> 4) * 8;
        const float* src = &W_attn[(size_t)j * (2 * H) + H + col];
        float4 x0 = *reinterpret_cast<const float4*>(src);
        float4 x1 = *reinterpret_cast<const float4*>(src + 4);
        *reinterpret_cast<half8v*>(&WfB[(size_t)u * 8]) = cvt8(x0, x1);
    } else {
        int gid = (blockIdx.x - 128) * 256 + threadIdx.x;  // 0..81919
        int k = gid >> 6, b = gid & 63;
        float v;
        if (k < 256)      v = emb[(size_t)inp[b] * E + k];
        else if (k < 768) v = loc[b * H + (k - 256)];
        else              v = hprev[b * H + (k - 768)];
        xprev_rm[b * 1280 + k] = v;       // [b][k]
    }
}

// ---------------------------------------------------------------------------
// K1: fused LSTM: gates via fp16 MFMA + in-block epilogue.
// grid 32 (u-range of 16 per block); wave w = gate w, j = w*512 + u0 + fr.
// A = xprev_rm rows b (4 frags of 16), K = 1280 = [x | h].
// Epilogue: all 4 gates for (b, u-range) are in LDS -> c,h inline.
// ---------------------------------------------------------------------------
__global__ __launch_bounds__(256) void k_lstm_f(const float* __restrict__ xprev_rm,
                                                const float* __restrict__ W_ih,
                                                const float* __restrict__ W_hh,
                                                const float* __restrict__ b_ih,
                                                const float* __restrict__ b_hh,
                                                const float* __restrict__ cprev,
                                                float* __restrict__ h_out,
                                                float* __restrict__ c_out,
                                                float* __restrict__ hnewT) {
    __shared__ float gl[4 * 16 * 64];     // [gate][uu][b] = 16 KB

    const int tid  = threadIdx.x;
    const int lane = tid & 63;
    const int w    = tid >> 6;            // gate index
    const int fr   = lane & 15;           // uu within range
    const int kb   = (lane >> 4) * 8;
    const int u0   = blockIdx.x * 16;
    const int j    = w * 512 + u0 + fr;   // gate row in W

    f32x4 acc[4];
    #pragma unroll
    for (int mf = 0; mf < 4; ++mf) acc[mf] = (f32x4){0.f, 0.f, 0.f, 0.f};

    const float* Arow = xprev_rm + (size_t)fr * 1280 + kb;   // b = mf*16+fr? see ap
    const float* Brow1 = W_ih + (size_t)j * KX + kb;
    for (int k0 = 0; k0 < KX; k0 += 32) {
        float4 b0 = *reinterpret_cast<const float4*>(Brow1 + k0);
        float4 b1 = *reinterpret_cast<const float4*>(Brow1 + k0 + 4);
        half8v bh = cvt8(b0, b1);
        #pragma unroll
        for (int mf = 0; mf < 4; ++mf) {
            const float* ap = Arow + (size_t)mf * 16 * 1280 + k0;
            float4 a0 = *reinterpret_cast<const float4*>(ap);
            float4 a1 = *reinterpret_cast<const float4*>(ap + 4);
            acc[mf] = __builtin_amdgcn_mfma_f32_16x16x32_f16(
                cvt8(a0, a1), bh, acc[mf], 0, 0, 0);
        }
    }
    const float* Brow2 = W_hh + (size_t)j * H + kb;
    for (int k0 = 0; k0 < H; k0 += 32) {
        float4 b0 = *reinterpret_cast<const float4*>(Brow2 + k0);
        float4 b1 = *reinterpret_cast<const float4*>(Brow2 + k0 + 4);
        half8v bh = cvt8(b0, b1);
        #pragma unroll
        for (int mf = 0; mf < 4; ++mf) {
            const float* ap = Arow + (size_t)mf * 16 * 1280 + KX + k0;
            float4 a0 = *reinterpret_cast<const float4*>(ap);
            float4 a1 = *reinterpret_cast<const float4*>(ap + 4);
            acc[mf] = __builtin_amdgcn_mfma_f32_16x16x32_f16(
                cvt8(a0, a1), bh, acc[mf], 0, 0, 0);
        }
    }
    float bo = b_ih[j] + b_hh[j];
    // C mapping: row b = mf*16 + (lane>>4)*4 + r, col = fr (uu).
    #pragma unroll
    for (int mf = 0; mf < 4; ++mf) {
        int bbase = mf * 16 + (lane >> 4) * 4;
        #pragma unroll
        for (int r = 0; r < 4; ++r)
            gl[(w * 16 + fr) * 64 + bbase + r] = acc[mf][r] + bo;
    }
    __syncthreads();
    // epilogue: 256 threads x 4 = 1024 (b,uu) pairs
    #pragma unroll
    for (int i = 0; i < 4; ++i) {
        int idx = tid * 4 + i;            // 0..1023
        int b = idx & 63, uu = idx >> 6;
        int u = u0 + uu;
        float ig = 1.f / (1.f + __expf(-gl[(0 * 16 + uu) * 64 + b]));
        float fg = 1.f / (1.f + __expf(-gl[(1 * 16 + uu) * 64 + b]));
        float gg = tanhf(gl[(2 * 16 + uu) * 64 + b]);
        float og = 1.f / (1.f + __expf(-gl[(3 * 16 + uu) * 64 + b]));
        float c = fg * cprev[b * H + u] + ig * gg;
        float h = og * tanhf(c);
        c_out[b * H + u] = c;
        h_out[b * H + u] = h;
        hnewT[u * 64 + b] = h;
    }
}

// ---------------------------------------------------------------------------
// K2: hW_jb[j][b] = b_attn[j] + sum_k h[b][k] * W_attn[j][k]
// ---------------------------------------------------------------------------
__global__ __launch_bounds__(256) void k_hw(const float* __restrict__ W_attn,
                                            const float* __restrict__ b_attn,
                                            const float* __restrict__ hT,
                                            float* __restrict__ hW_jb) {
    int j = blockIdx.x * 4 + (threadIdx.x >> 6);
    int b = threadIdx.x & 63;
    float a0 = 0.f, a1 = 0.f, a2 = 0.f, a3 = 0.f;
    const float* Wr = &W_attn[(size_t)j * (2 * H)];
    for (int k = 0; k < H; k += 4) {
        float4 wv = *reinterpret_cast<const float4*>(&Wr[k]);
        a0 += wv.x * hT[(k + 0) * 64 + b];
        a1 += wv.y * hT[(k + 1) * 64 + b];
        a2 += wv.z * hT[(k + 2) * 64 + b];
        a3 += wv.w * hT[(k + 3) * 64 + b];
    }
    hW_jb[j * 64 + b] = b_attn[j] + ((a0 + a1) + (a2 + a3));
}

// ---------------------------------------------------------------------------
// K3: energy GEMM v12 (proven 101-102 us): BK=32, 2 barriers/phase,
// glds-direct both operands; A raw fp32 with XOR-coalesced per-lane sources;
// B fragment-ordered fp16.  XCD swizzle.  __launch_bounds__(256,4).
// ---------------------------------------------------------------------------
__global__ __launch_bounds__(256, 4) void k_energy_v12(
        const float* __restrict__ enc,
        const unsigned short* __restrict__ WfB,
        const float* __restrict__ hW,
        const float* __restrict__ beta,
        float* __restrict__ partial_e) {
    __shared__ float Af[4096];            // 16 KB
    __shared__ unsigned short Bh2[4096];  //  8 KB
    __shared__ float red[2][128];

    const int tid  = threadIdx.x;
    const int lane = tid & 63;
    const int w    = tid >> 6;
    const int wm = w >> 1;
    const int wn = w & 1;
    const int bid = blockIdx.x;
    const int xcd = bid & 7;
    const int loc = bid >> 3;
    const int mt  = xcd * 64 + (loc >> 2);
    const int jt  = loc & 3;
    const int m0 = mt * 128;
    const int j0 = jt * 128;

    const int fr = lane & 15;
    const int g  = lane >> 4;

    const float* asrcA[4];
    #pragma unroll
    for (int i = 0; i < 4; ++i) {
        int c0 = (w * 4 + i) * 64 + lane;
        int row = c0 >> 3;
        int sc = (lane & 7) ^ (row & 7);
        asrcA[i] = enc + (size_t)(m0 + row) * H + sc * 4;
    }
    const size_t bbase = (size_t)jt * 16 * 512;   // chunks

    f32x4 acc[4][4];
    #pragma unroll
    for (int i = 0; i < 4; ++i)
        #pragma unroll
        for (int j = 0; j < 4; ++j) acc[i][j] = (f32x4){0.f, 0.f, 0.f, 0.f};

    for (int kt = 0; kt < 16; ++kt) {
        #pragma unroll
        for (int i = 0; i < 4; ++i)
            glds16(asrcA[i] + kt * 32, &Af[((w * 4 + i) * 64 + lane) * 4]);
        #pragma unroll
        for (int i = 0; i < 2; ++i)
            glds16(WfB + (bbase + (size_t)kt * 512 + (w * 2 + i) * 64 + lane) * 8,
                   &Bh2[((w * 2 + i) * 64 + lane) * 8]);
        __syncthreads();
        half8v a_h[4], b_h[4];
        #pragma unroll
        for (int mf = 0; mf < 4; ++mf) {
            int R = wm * 64 + mf * 16 + fr;
            int p0 = (2 * g) ^ (R & 7);
            int p1 = p0 ^ 1;
            float4 f0 = *reinterpret_cast<const float4*>(&Af[(R * 8 + p0) * 4]);
            float4 f1 = *reinterpret_cast<const float4*>(&Af[(R * 8 + p1) * 4]);
            a_h[mf] = cvt8(f0, f1);
        }
        #pragma unroll
        for (int nf = 0; nf < 4; ++nf)
            b_h[nf] = *reinterpret_cast<const half8v*>(
                &Bh2[((wn * 4 + nf) * 64 + lane) * 8]);
        #pragma unroll
        for (int mf = 0; mf < 4; ++mf)
            #pragma unroll
            for (int nf = 0; nf < 4; ++nf)
                acc[mf][nf] = __builtin_amdgcn_mfma_f32_16x16x32_f16(
                    a_h[mf], b_h[nf], acc[mf][nf], 0, 0, 0);
        __syncthreads();
    }

    float psum[4][4];
    #pragma unroll
    for (int i = 0; i < 4; ++i)
        #pragma unroll
        for (int r = 0; r < 4; ++r) psum[i][r] = 0.f;
    #pragma unroll
    for (int nf = 0; nf < 4; ++nf) {
        int jj = j0 + wn * 64 + nf * 16 + (lane & 15);
        float bet = beta[jj];
        #pragma unroll
        for (int mf = 0; mf < 4; ++mf) {
            int b_base = (wm * 64 + mf * 16 + (lane >> 4) * 4) & 63;
            float4 hw4 = *reinterpret_cast<const float4*>(&hW[jj * 64 + b_base]);
            float hwv[4] = {hw4.x, hw4.y, hw4.z, hw4.w};
            #pragma unroll
            for (int r = 0; r < 4; ++r) {
                float e = acc[mf][nf][r] + hwv[r];
                float ex = __expf(2.f * e);
                psum[mf][r] += bet * (1.f - 2.f / (ex + 1.f));
            }
        }
    }
    #pragma unroll
    for (int mf = 0; mf < 4; ++mf)
        #pragma unroll
        for (int r = 0; r < 4; ++r) {
            float v = psum[mf][r];
            v += __shfl_xor(v, 1);
            v += __shfl_xor(v, 2);
            v += __shfl_xor(v, 4);
            v += __shfl_xor(v, 8);
            psum[mf][r] = v;
        }
    __syncthreads();
    if ((lane & 15) == 0) {
        #pragma unroll
        for (int mf = 0; mf < 4; ++mf)
            #pragma unroll
            for (int r = 0; r < 4; ++r)
                red[wn][wm * 64 + mf * 16 + (lane >> 4) * 4 + r] = psum[mf][r];
    }
    __syncthreads();
    if (tid < 128)
        partial_e[(size_t)jt * M_TOT + m0 + tid] = red[0][tid] + red[1][tid];
}

// ---------------------------------------------------------------------------
// K4: softmax over l per b.  e[l] = sum_{nb<4} partial_e[nb][l*64+b]
// ---------------------------------------------------------------------------
__global__ __launch_bounds__(256) void k_softmax_l(const float* __restrict__ partial_e,
                                                   float* __restrict__ attn_w) {
    int b = blockIdx.x;
    int tid = threadIdx.x;
    float el[4];
    float m = -1e30f;
    #pragma unroll
    for (int i = 0; i < 4; ++i) {
        int l = i * 256 + tid;
        float e = 0.f;
        #pragma unroll
        for (int nb = 0; nb < 4; ++nb)
            e += partial_e[(size_t)nb * M_TOT + l * 64 + b];
        el[i] = e;
        m = fmaxf(m, e);
    }
    #pragma unroll
    for (int s = 1; s < 64; s <<= 1) m = fmaxf(m, __shfl_xor(m, s));
    __shared__ float redm[4];
    if ((tid & 63) == 0) redm[tid >> 6] = m;
    __syncthreads();
    m = fmaxf(fmaxf(redm[0], redm[1]), fmaxf(redm[2], redm[3]));
    float s = 0.f;
    #pragma unroll
    for (int i = 0; i < 4; ++i) { el[i] = __expf(el[i] - m); s += el[i]; }
    #pragma unroll
    for (int sh = 1; sh < 64; sh <<= 1) s += __shfl_xor(s, sh);
    __shared__ float reds[4];
    if ((tid & 63) == 0) reds[tid >> 6] = s;
    __syncthreads();
    s = reds[0] + reds[1] + reds[2] + reds[3];
    float inv = 1.f / s;
    #pragma unroll
    for (int i = 0; i < 4; ++i)
        attn_w[(i * 256 + tid) * 64 + b] = el[i] * inv;
}

// ---------------------------------------------------------------------------
// K5: context partials over l chunks. float4, 128 threads.
// ---------------------------------------------------------------------------
__global__ __launch_bounds__(128) void k_ctx_part(const float* __restrict__ attn_w,
                                                  const float* __restrict__ enc,
                                                  float* __restrict__ ctx_part) {
    int chunk = blockIdx.x, b = blockIdx.y;
    int h = threadIdx.x * 4;
    float4 acc = {0.f, 0.f, 0.f, 0.f};
    for (int i = 0; i < 32; ++i) {
        int l = chunk * 32 + i;
        float w = attn_w[l * 64 + b];
        float4 e4 = *reinterpret_cast<const float4*>(
            &enc[((size_t)l * 64 + b) * H + h]);
        acc.x += w * e4.x;
        acc.y += w * e4.y;
        acc.z += w * e4.z;
        acc.w += w * e4.w;
    }
    *reinterpret_cast<float4*>(&ctx_part[((size_t)(chunk * 64 + b)) * H + h]) = acc;
}

__global__ __launch_bounds__(256) void k_ctx_reduce(const float* __restrict__ ctx_part,
                                                    float* __restrict__ ctxT) {
    int gid = blockIdx.x * 256 + threadIdx.x;
    int b = gid >> 9, h = gid & 511;
    float s = 0.f;
    for (int c = 0; c < 32; ++c)
        s += ctx_part[((size_t)(c * 64 + b)) * H + h];
    ctxT[h * 64 + b] = s;
}

// ---------------------------------------------------------------------------
// K6: co[b][j] = tanh([h | ctx] . W_oc[j] + b_oc[j])
// ---------------------------------------------------------------------------
__global__ __launch_bounds__(256) void k_co(const float* __restrict__ W_oc,
                                            const float* __restrict__ b_oc,
                                            const float* __restrict__ hT,
                                            const float* __restrict__ ctxT,
                                            float* __restrict__ co_out) {
    int j = blockIdx.x * 4 + (threadIdx.x >> 6);
    int b = threadIdx.x & 63;
    float a0 = 0.f, a1 = 0.f, a2 = 0.f, a3 = 0.f;
    const float* Wr = &W_oc[(size_t)j * (2 * H)];
    for (int k = 0; k < H; k += 4) {
        float4 wv = *reinterpret_cast<const float4*>(&Wr[k]);
        a0 += wv.x * hT[(k + 0) * 64 + b];
        a1 += wv.y * hT[(k + 1) * 64 + b];
        a2 += wv.z * hT[(k + 2) * 64 + b];
        a3 += wv.w * hT[(k + 3) * 64 + b];
    }
    const float* Wr2 = Wr + H;
    for (int k = 0; k < H; k += 4) {
        float4 wv = *reinterpret_cast<const float4*>(&Wr2[k]);
        a0 += wv.x * ctxT[(k + 0) * 64 + b];
        a1 += wv.y * ctxT[(k + 1) * 64 + b];
        a2 += wv.z * ctxT[(k + 2) * 64 + b];
        a3 += wv.w * ctxT[(k + 3) * 64 + b];
    }
    co_out[b * H + j] = tanhf(b_oc[j] + ((a0 + a1) + (a2 + a3)));
}

// ---------------------------------------------------------------------------
// K7: logits, no-LDS no-barrier fp16 MFMA (unchanged).
// ---------------------------------------------------------------------------
__global__ __launch_bounds__(256) void k_logits_v3(const float* __restrict__ co,
                                                   const float* __restrict__ W_out,
                                                   const float* __restrict__ b_out,
                                                   float* __restrict__ logits) {
    const int tid  = threadIdx.x;
    const int lane = tid & 63;
    const int w    = tid >> 6;
    const int fr   = lane & 15;
    const int kb   = (lane >> 4) * 8;
    const int j    = blockIdx.x * 64 + w * 16 + fr;

    f32x4 acc[4];
    #pragma unroll
    for (int mf = 0; mf < 4; ++mf) acc[mf] = (f32x4){0.f, 0.f, 0.f, 0.f};

    const float* Arow = &co[(size_t)fr * H + kb];
    const float* Brow = &W_out[(size_t)j * H + kb];

    for (int k0 = 0; k0 < H; k0 += 32) {
        float4 b0 = *reinterpret_cast<const float4*>(Brow + k0);
        float4 b1 = *reinterpret_cast<const float4*>(Brow + k0 + 4);
        half8v bh = cvt8(b0, b1);
        #pragma unroll
        for (int mf = 0; mf < 4; ++mf) {
            const float* ap = Arow + (size_t)mf * 16 * H + k0;
            float4 a0 = *reinterpret_cast<const float4*>(ap);
            float4 a1 = *reinterpret_cast<const float4*>(ap + 4);
            half8v ah = cvt8(a0, a1);
            acc[mf] = __builtin_amdgcn_mfma_f32_16x16x32_f16(ah, bh, acc[mf], 0, 0, 0);
        }
    }
    float bo = b_out[j];
    #pragma unroll
    for (int mf = 0; mf < 4; ++mf) {
        int mbase = mf * 16 + (lane >> 4) * 4;
        #pragma unroll
        for (int r = 0; r < 4; ++r)
            logits[(size_t)(mbase + r) * V + j] = acc[mf][r] + bo;
    }
}

// ---------------------------------------------------------------------------
// K8a: per-(b, chunk) partial max & expsum. grid (8 chunks, 64 b), 256 thr.
// ---------------------------------------------------------------------------
__global__ __launch_bounds__(256) void k_lsm_part(const float* __restrict__ logits,
                                                  float* __restrict__ pmax,
                                                  float* __restrict__ psum) {
    int chunk = blockIdx.x, b = blockIdx.y;
    int tid = threadIdx.x;
    const float* row = &logits[(size_t)b * V + chunk * 4000];
    float v[16];
    float m = -1e30f;
    #pragma unroll
    for (int t = 0; t < 16; ++t) {
        int i = t * 256 + tid;
        v[t] = (i < 4000) ? row[i] : -1e30f;
        m = fmaxf(m, v[t]);
    }
    #pragma unroll
    for (int s = 1; s < 64; s <<= 1) m = fmaxf(m, __shfl_xor(m, s));
    __shared__ float redm[4];
    if ((tid & 63) == 0) redm[tid >> 6] = m;
    __syncthreads();
    m = fmaxf(fmaxf(redm[0], redm[1]), fmaxf(redm[2], redm[3]));
    float s = 0.f;
    #pragma unroll
    for (int t = 0; t < 16; ++t) s += __expf(v[t] - m);
    #pragma unroll
    for (int sh = 1; sh < 64; sh <<= 1) s += __shfl_xor(s, sh);
    __shared__ float reds[4];
    if ((tid & 63) == 0) reds[tid >> 6] = s;
    __syncthreads();
    if (tid == 0) {
        pmax[chunk * 64 + b] = m;
        psum[chunk * 64 + b] = reds[0] + reds[1] + reds[2] + reds[3];
    }
}

// K8b: out = logits - lse[b], lse computed inline from the 8 partials.
__global__ __launch_bounds__(256) void k_lsm_write(const float* __restrict__ logits,
                                                   const float* __restrict__ pmax,
                                                   const float* __restrict__ psum,
                                                   float* __restrict__ out) {
    size_t i4 = ((size_t)blockIdx.x * 256 + threadIdx.x) * 4;
    int b = (int)(i4 / V);
    float m = -1e30f;
    #pragma unroll
    for (int c = 0; c < 8; ++c) m = fmaxf(m, pmax[c * 64 + b]);
    float s = 0.f;
    #pragma unroll
    for (int c = 0; c < 8; ++c) s += psum[c * 64 + b] * __expf(pmax[c * 64 + b] - m);
    float l = m + __logf(s);
    float4 x = *reinterpret_cast<const float4*>(&logits[i4]);
    x.x -= l; x.y -= l; x.z -= l; x.w -= l;
    *reinterpret_cast<float4*>(&out[i4]) = x;
}

// ---------------------------------------------------------------------------
extern "C" void kernel_launch(void* const* d_in, const int* in_sizes, int n_in,
                              void* d_out, int out_size, void* d_ws, size_t ws_size,
                              hipStream_t stream) {
    const int*   inp    = (const int*)  d_in[0];
    const float* loc    = (const float*)d_in[1];
    const float* hprev  = (const float*)d_in[2];
    const float* cprev  = (const float*)d_in[3];
    const float* enc    = (const float*)d_in[4];
    const float* emb    = (const float*)d_in[5];
    const float* W_ih   = (const float*)d_in[6];
    const float* W_hh   = (const float*)d_in[7];
    const float* b_ih   = (const float*)d_in[8];
    const float* b_hh   = (const float*)d_in[9];
    const float* W_attn = (const float*)d_in[10];
    const float* b_attn = (const float*)d_in[11];
    const float* beta   = (const float*)d_in[12];
    const float* W_oc   = (const float*)d_in[13];
    const float* b_oc   = (const float*)d_in[14];
    const float* W_out  = (const float*)d_in[15];
    const float* b_out  = (const float*)d_in[16];

    float* out = (float*)d_out;
    float* out_co = out + (size_t)B * V;
    float* out_h  = out_co + B * H;
    float* out_c  = out_h  + B * H;

    float* ws = (float*)d_ws;
    float* xprev_rm = ws;                                //    81920
    float* hnewT   = xprev_rm + 1280 * 64;               //    32768
    float* hW      = hnewT  + H * 64;                    //    32768
    float* pe      = hW     + H * 64;                    //  4*65536
    float* attnw   = pe     + 4 * M_TOT;                 //    65536
    float* ctxp    = attnw  + M_TOT;                     //  1048576
    float* ctxT    = ctxp   + 32 * 64 * H;               //    32768
    float* logits  = ctxT   + H * 64;                    //  2048000
    float* pmax    = logits + (size_t)B * V;             //      512
    float* psum    = pmax   + 512;                       //      512
    unsigned short* WfB = (unsigned short*)(psum + 512); //   262144 u16

    k_prep  <<<448, 256, 0, stream>>>(W_attn, WfB, inp, loc, hprev, emb, xprev_rm);
    k_lstm_f<<<32, 256, 0, stream>>>(xprev_rm, W_ih, W_hh, b_ih, b_hh, cprev,
                                     out_h, out_c, hnewT);
    k_hw    <<<128, 256, 0, stream>>>(W_attn, b_attn, hnewT, hW);
    k_energy_v12<<<2048, 256, 0, stream>>>(enc, WfB, hW, beta, pe);
    k_softmax_l<<<64, 256, 0, stream>>>(pe, attnw);
    k_ctx_part <<<dim3(32, 64), 128, 0, stream>>>(attnw, enc, ctxp);
    k_ctx_reduce<<<128, 256, 0, stream>>>(ctxp, ctxT);
    k_co    <<<128, 256, 0, stream>>>(W_oc, b_oc, hnewT, ctxT, out_co);
    k_logits_v3<<<500, 256, 0, stream>>>(out_co, W_out, b_out, logits);
    k_lsm_part<<<dim3(8, 64), 256, 0, stream>>>(logits, pmax, psum);
    k_lsm_write<<<2000, 256, 0, stream>>>(logits, pmax, psum, out);
}

// Round 22
// 262.903 us; speedup vs baseline: 1.0030x; 1.0030x over previous
//
#include <hip/hip_runtime.h>
#include <hip/hip_bf16.h>
#include <cstddef>

// Problem dims
#define H   512
#define E   256
#define V   32000
#define L   1024
#define B   64
#define KX  768      // E + H
#define G2  2048     // 4*H
#define M_TOT 65536  // L*B

typedef __attribute__((ext_vector_type(8))) _Float16 half8v;
typedef __attribute__((ext_vector_type(4))) float f32x4;

__device__ __forceinline__ half8v cvt8(float4 x0, float4 x1) {
    union { half8v v; _Float16 u[8]; } hv;
    hv.u[0] = (_Float16)x0.x; hv.u[1] = (_Float16)x0.y;
    hv.u[2] = (_Float16)x0.z; hv.u[3] = (_Float16)x0.w;
    hv.u[4] = (_Float16)x1.x; hv.u[5] = (_Float16)x1.y;
    hv.u[6] = (_Float16)x1.z; hv.u[7] = (_Float16)x1.w;
    return hv.v;
}

// async global->LDS, 16B per lane; LDS dst = wave-uniform base + lane*16.
__device__ __forceinline__ void glds16(const void* g, void* l) {
    __builtin_amdgcn_global_load_lds(
        (const __attribute__((address_space(1))) void*)g,
        (__attribute__((address_space(3))) void*)l, 16, 0, 0);
}

// ---------------------------------------------------------------------------
// K-prep: blocks 0..127 -> W_attn[:,H:] into fragment-ordered fp16 WfB;
//         blocks 128..447 -> build xprev_rm (b-major [b][1280]).
// ---------------------------------------------------------------------------
__global__ __launch_bounds__(256) void k_prep(const float* __restrict__ W_attn,
                                              unsigned short* __restrict__ WfB,
                                              const int* __restrict__ inp,
                                              const float* __restrict__ loc,
                                              const float* __restrict__ hprev,
                                              const float* __restrict__ emb,
                                              float* __restrict__ xprev_rm) {
    if (blockIdx.x < 128) {
        int u = blockIdx.x * 256 + threadIdx.x;   // 0..32767 chunks
        int lane = u & 63;
        int rest = u >> 6;                        // (jt*16+kt)*8 + f
        int f = rest & 7;
        int kt = (rest >> 3) & 15;
        int jt = rest >> 7;
        int wn = f >> 2, nf = f & 3;
        int j = jt * 128 + wn * 64 + nf * 16 + (lane & 15);
        int col = kt * 32 + (lane >> 4) * 8;
        const float* src = &W_attn[(size_t)j * (2 * H) + H + col];
        float4 x0 = *reinterpret_cast<const float4*>(src);
        float4 x1 = *reinterpret_cast<const float4*>(src + 4);
        *reinterpret_cast<half8v*>(&WfB[(size_t)u * 8]) = cvt8(x0, x1);
    } else {
        int gid = (blockIdx.x - 128) * 256 + threadIdx.x;  // 0..81919
        int k = gid >> 6, b = gid & 63;
        float v;
        if (k < 256)      v = emb[(size_t)inp[b] * E + k];
        else if (k < 768) v = loc[b * H + (k - 256)];
        else              v = hprev[b * H + (k - 768)];
        xprev_rm[b * 1280 + k] = v;       // [b][k]
    }
}

// ---------------------------------------------------------------------------
// K1: fused LSTM: gates via fp16 MFMA + in-block epilogue (R21 proven).
// ---------------------------------------------------------------------------
__global__ __launch_bounds__(256) void k_lstm_f(const float* __restrict__ xprev_rm,
                                                const float* __restrict__ W_ih,
                                                const float* __restrict__ W_hh,
                                                const float* __restrict__ b_ih,
                                                const float* __restrict__ b_hh,
                                                const float* __restrict__ cprev,
                                                float* __restrict__ h_out,
                                                float* __restrict__ c_out,
                                                float* __restrict__ hnewT) {
    __shared__ float gl[4 * 16 * 64];     // [gate][uu][b] = 16 KB

    const int tid  = threadIdx.x;
    const int lane = tid & 63;
    const int w    = tid >> 6;            // gate index
    const int fr   = lane & 15;           // uu within range
    const int kb   = (lane >> 4) * 8;
    const int u0   = blockIdx.x * 16;
    const int j    = w * 512 + u0 + fr;   // gate row in W

    f32x4 acc[4];
    #pragma unroll
    for (int mf = 0; mf < 4; ++mf) acc[mf] = (f32x4){0.f, 0.f, 0.f, 0.f};

    const float* Arow = xprev_rm + (size_t)fr * 1280 + kb;
    const float* Brow1 = W_ih + (size_t)j * KX + kb;
    for (int k0 = 0; k0 < KX; k0 += 32) {
        float4 b0 = *reinterpret_cast<const float4*>(Brow1 + k0);
        float4 b1 = *reinterpret_cast<const float4*>(Brow1 + k0 + 4);
        half8v bh = cvt8(b0, b1);
        #pragma unroll
        for (int mf = 0; mf < 4; ++mf) {
            const float* ap = Arow + (size_t)mf * 16 * 1280 + k0;
            float4 a0 = *reinterpret_cast<const float4*>(ap);
            float4 a1 = *reinterpret_cast<const float4*>(ap + 4);
            acc[mf] = __builtin_amdgcn_mfma_f32_16x16x32_f16(
                cvt8(a0, a1), bh, acc[mf], 0, 0, 0);
        }
    }
    const float* Brow2 = W_hh + (size_t)j * H + kb;
    for (int k0 = 0; k0 < H; k0 += 32) {
        float4 b0 = *reinterpret_cast<const float4*>(Brow2 + k0);
        float4 b1 = *reinterpret_cast<const float4*>(Brow2 + k0 + 4);
        half8v bh = cvt8(b0, b1);
        #pragma unroll
        for (int mf = 0; mf < 4; ++mf) {
            const float* ap = Arow + (size_t)mf * 16 * 1280 + KX + k0;
            float4 a0 = *reinterpret_cast<const float4*>(ap);
            float4 a1 = *reinterpret_cast<const float4*>(ap + 4);
            acc[mf] = __builtin_amdgcn_mfma_f32_16x16x32_f16(
                cvt8(a0, a1), bh, acc[mf], 0, 0, 0);
        }
    }
    float bo = b_ih[j] + b_hh[j];
    #pragma unroll
    for (int mf = 0; mf < 4; ++mf) {
        int bbase = mf * 16 + (lane >> 4) * 4;
        #pragma unroll
        for (int r = 0; r < 4; ++r)
            gl[(w * 16 + fr) * 64 + bbase + r] = acc[mf][r] + bo;
    }
    __syncthreads();
    #pragma unroll
    for (int i = 0; i < 4; ++i) {
        int idx = tid * 4 + i;            // 0..1023
        int b = idx & 63, uu = idx >> 6;
        int u = u0 + uu;
        float ig = 1.f / (1.f + __expf(-gl[(0 * 16 + uu) * 64 + b]));
        float fg = 1.f / (1.f + __expf(-gl[(1 * 16 + uu) * 64 + b]));
        float gg = tanhf(gl[(2 * 16 + uu) * 64 + b]);
        float og = 1.f / (1.f + __expf(-gl[(3 * 16 + uu) * 64 + b]));
        float c = fg * cprev[b * H + u] + ig * gg;
        float h = og * tanhf(c);
        c_out[b * H + u] = c;
        h_out[b * H + u] = h;
        hnewT[u * 64 + b] = h;
    }
}

// ---------------------------------------------------------------------------
// K2: hW_jb[j][b] = b_attn[j] + sum_k h[b][k] * W_attn[j][k]
// ---------------------------------------------------------------------------
__global__ __launch_bounds__(256) void k_hw(const float* __restrict__ W_attn,
                                            const float* __restrict__ b_attn,
                                            const float* __restrict__ hT,
                                            float* __restrict__ hW_jb) {
    int j = blockIdx.x * 4 + (threadIdx.x >> 6);
    int b = threadIdx.x & 63;
    float a0 = 0.f, a1 = 0.f, a2 = 0.f, a3 = 0.f;
    const float* Wr = &W_attn[(size_t)j * (2 * H)];
    for (int k = 0; k < H; k += 4) {
        float4 wv = *reinterpret_cast<const float4*>(&Wr[k]);
        a0 += wv.x * hT[(k + 0) * 64 + b];
        a1 += wv.y * hT[(k + 1) * 64 + b];
        a2 += wv.z * hT[(k + 2) * 64 + b];
        a3 += wv.w * hT[(k + 3) * 64 + b];
    }
    hW_jb[j * 64 + b] = b_attn[j] + ((a0 + a1) + (a2 + a3));
}

// ---------------------------------------------------------------------------
// K3: energy GEMM v15 = v12's glds-direct raw-fp32-A scheme at BK=64:
// 8 phases x {12 glds/thread-group -> barrier -> 2x(frag reads + 16 MFMA)
// -> barrier}.  A chunk permutation sc = (cp&8)|((cp&7)^(row&7)) stays in
// the row's 128B half (coalesced) and is conflict-free per 8-lane group.
// B fragment-ordered fp16 (linear glds).  XCD swizzle.  (256,3), 49 KB LDS.
// ---------------------------------------------------------------------------
__global__ __launch_bounds__(256, 3) void k_energy_v15(
        const float* __restrict__ enc,
        const unsigned short* __restrict__ WfB,
        const float* __restrict__ hW,
        const float* __restrict__ beta,
        float* __restrict__ partial_e) {
    __shared__ float Af[8192];            // 2048 chunks * 4 floats = 32 KB
    __shared__ unsigned short Bh2[8192];  // 1024 chunks * 8 halves = 16 KB
    __shared__ float red[2][128];

    const int tid  = threadIdx.x;
    const int lane = tid & 63;
    const int w    = tid >> 6;
    const int wm = w >> 1;
    const int wn = w & 1;
    const int bid = blockIdx.x;
    const int xcd = bid & 7;
    const int loc = bid >> 3;
    const int mt  = xcd * 64 + (loc >> 2);
    const int jt  = loc & 3;
    const int m0 = mt * 128;
    const int j0 = jt * 128;

    const int fr = lane & 15;
    const int g  = lane >> 4;

    // A glds sources (8/thread): chunk cid = (w*8+i)*64+lane; row = cid>>4,
    // cp = cid&15; stored chunk cp holds source chunk sc = (cp&8)|((cp&7)^(row&7)).
    const float* asrcA[8];
    #pragma unroll
    for (int i = 0; i < 8; ++i) {
        int cid = (w * 8 + i) * 64 + lane;
        int row = cid >> 4;
        int cp  = cid & 15;
        int sc  = (cp & 8) | ((cp & 7) ^ (row & 7));
        asrcA[i] = enc + (size_t)(m0 + row) * H + sc * 4;
    }
    const size_t bbase = (size_t)jt * 8192;   // chunks (16 kt * 512)

    f32x4 acc[4][4];
    #pragma unroll
    for (int i = 0; i < 4; ++i)
        #pragma unroll
        for (int j = 0; j < 4; ++j) acc[i][j] = (f32x4){0.f, 0.f, 0.f, 0.f};

    for (int kt2 = 0; kt2 < 8; ++kt2) {
        #pragma unroll
        for (int i = 0; i < 8; ++i)
            glds16(asrcA[i] + kt2 * 64, &Af[((w * 8 + i) * 64 + lane) * 4]);
        #pragma unroll
        for (int i = 0; i < 4; ++i)
            glds16(WfB + (bbase + (size_t)kt2 * 1024 + (w * 4 + i) * 64 + lane) * 8,
                   &Bh2[((w * 4 + i) * 64 + lane) * 8]);
        __syncthreads();                   // drain DMA -> tile resident
        #pragma unroll
        for (int kh = 0; kh < 2; ++kh) {
            half8v a_h[4], b_h[4];
            #pragma unroll
            for (int mf = 0; mf < 4; ++mf) {
                int R = wm * 64 + mf * 16 + fr;
                int p0 = (kh * 8) | ((2 * g) ^ (R & 7));
                int p1 = p0 ^ 1;
                float4 f0 = *reinterpret_cast<const float4*>(&Af[(R * 16 + p0) * 4]);
                float4 f1 = *reinterpret_cast<const float4*>(&Af[(R * 16 + p1) * 4]);
                a_h[mf] = cvt8(f0, f1);
            }
            #pragma unroll
            for (int nf = 0; nf < 4; ++nf)
                b_h[nf] = *reinterpret_cast<const half8v*>(
                    &Bh2[((kh * 8 + wn * 4 + nf) * 64 + lane) * 8]);
            #pragma unroll
            for (int mf = 0; mf < 4; ++mf)
                #pragma unroll
                for (int nf = 0; nf < 4; ++nf)
                    acc[mf][nf] = __builtin_amdgcn_mfma_f32_16x16x32_f16(
                        a_h[mf], b_h[nf], acc[mf][nf], 0, 0, 0);
        }
        __syncthreads();                   // protect LDS from next DMA
    }

    float psum[4][4];
    #pragma unroll
    for (int i = 0; i < 4; ++i)
        #pragma unroll
        for (int r = 0; r < 4; ++r) psum[i][r] = 0.f;
    #pragma unroll
    for (int nf = 0; nf < 4; ++nf) {
        int jj = j0 + wn * 64 + nf * 16 + (lane & 15);
        float bet = beta[jj];
        #pragma unroll
        for (int mf = 0; mf < 4; ++mf) {
            int b_base = (wm * 64 + mf * 16 + (lane >> 4) * 4) & 63;
            float4 hw4 = *reinterpret_cast<const float4*>(&hW[jj * 64 + b_base]);
            float hwv[4] = {hw4.x, hw4.y, hw4.z, hw4.w};
            #pragma unroll
            for (int r = 0; r < 4; ++r) {
                float e = acc[mf][nf][r] + hwv[r];
                float ex = __expf(2.f * e);
                psum[mf][r] += bet * (1.f - 2.f / (ex + 1.f));
            }
        }
    }
    #pragma unroll
    for (int mf = 0; mf < 4; ++mf)
        #pragma unroll
        for (int r = 0; r < 4; ++r) {
            float v = psum[mf][r];
            v += __shfl_xor(v, 1);
            v += __shfl_xor(v, 2);
            v += __shfl_xor(v, 4);
            v += __shfl_xor(v, 8);
            psum[mf][r] = v;
        }
    __syncthreads();
    if ((lane & 15) == 0) {
        #pragma unroll
        for (int mf = 0; mf < 4; ++mf)
            #pragma unroll
            for (int r = 0; r < 4; ++r)
                red[wn][wm * 64 + mf * 16 + (lane >> 4) * 4 + r] = psum[mf][r];
    }
    __syncthreads();
    if (tid < 128)
        partial_e[(size_t)jt * M_TOT + m0 + tid] = red[0][tid] + red[1][tid];
}

// ---------------------------------------------------------------------------
// K4: softmax over l per b.  e[l] = sum_{nb<4} partial_e[nb][l*64+b]
// ---------------------------------------------------------------------------
__global__ __launch_bounds__(256) void k_softmax_l(const float* __restrict__ partial_e,
                                                   float* __restrict__ attn_w) {
    int b = blockIdx.x;
    int tid = threadIdx.x;
    float el[4];
    float m = -1e30f;
    #pragma unroll
    for (int i = 0; i < 4; ++i) {
        int l = i * 256 + tid;
        float e = 0.f;
        #pragma unroll
        for (int nb = 0; nb < 4; ++nb)
            e += partial_e[(size_t)nb * M_TOT + l * 64 + b];
        el[i] = e;
        m = fmaxf(m, e);
    }
    #pragma unroll
    for (int s = 1; s < 64; s <<= 1) m = fmaxf(m, __shfl_xor(m, s));
    __shared__ float redm[4];
    if ((tid & 63) == 0) redm[tid >> 6] = m;
    __syncthreads();
    m = fmaxf(fmaxf(redm[0], redm[1]), fmaxf(redm[2], redm[3]));
    float s = 0.f;
    #pragma unroll
    for (int i = 0; i < 4; ++i) { el[i] = __expf(el[i] - m); s += el[i]; }
    #pragma unroll
    for (int sh = 1; sh < 64; sh <<= 1) s += __shfl_xor(s, sh);
    __shared__ float reds[4];
    if ((tid & 63) == 0) reds[tid >> 6] = s;
    __syncthreads();
    s = reds[0] + reds[1] + reds[2] + reds[3];
    float inv = 1.f / s;
    #pragma unroll
    for (int i = 0; i < 4; ++i)
        attn_w[(i * 256 + tid) * 64 + b] = el[i] * inv;
}

// ---------------------------------------------------------------------------
// K5: context partials over l chunks. float4, 128 threads.
// ---------------------------------------------------------------------------
__global__ __launch_bounds__(128) void k_ctx_part(const float* __restrict__ attn_w,
                                                  const float* __restrict__ enc,
                                                  float* __restrict__ ctx_part) {
    int chunk = blockIdx.x, b = blockIdx.y;
    int h = threadIdx.x * 4;
    float4 acc = {0.f, 0.f, 0.f, 0.f};
    for (int i = 0; i < 32; ++i) {
        int l = chunk * 32 + i;
        float w = attn_w[l * 64 + b];
        float4 e4 = *reinterpret_cast<const float4*>(
            &enc[((size_t)l * 64 + b) * H + h]);
        acc.x += w * e4.x;
        acc.y += w * e4.y;
        acc.z += w * e4.z;
        acc.w += w * e4.w;
    }
    *reinterpret_cast<float4*>(&ctx_part[((size_t)(chunk * 64 + b)) * H + h]) = acc;
}

__global__ __launch_bounds__(256) void k_ctx_reduce(const float* __restrict__ ctx_part,
                                                    float* __restrict__ ctxT) {
    int gid = blockIdx.x * 256 + threadIdx.x;
    int b = gid >> 9, h = gid & 511;
    float s = 0.f;
    for (int c = 0; c < 32; ++c)
        s += ctx_part[((size_t)(c * 64 + b)) * H + h];
    ctxT[h * 64 + b] = s;
}

// ---------------------------------------------------------------------------
// K6: co[b][j] = tanh([h | ctx] . W_oc[j] + b_oc[j])
// ---------------------------------------------------------------------------
__global__ __launch_bounds__(256) void k_co(const float* __restrict__ W_oc,
                                            const float* __restrict__ b_oc,
                                            const float* __restrict__ hT,
                                            const float* __restrict__ ctxT,
                                            float* __restrict__ co_out) {
    int j = blockIdx.x * 4 + (threadIdx.x >> 6);
    int b = threadIdx.x & 63;
    float a0 = 0.f, a1 = 0.f, a2 = 0.f, a3 = 0.f;
    const float* Wr = &W_oc[(size_t)j * (2 * H)];
    for (int k = 0; k < H; k += 4) {
        float4 wv = *reinterpret_cast<const float4*>(&Wr[k]);
        a0 += wv.x * hT[(k + 0) * 64 + b];
        a1 += wv.y * hT[(k + 1) * 64 + b];
        a2 += wv.z * hT[(k + 2) * 64 + b];
        a3 += wv.w * hT[(k + 3) * 64 + b];
    }
    const float* Wr2 = Wr + H;
    for (int k = 0; k < H; k += 4) {
        float4 wv = *reinterpret_cast<const float4*>(&Wr2[k]);
        a0 += wv.x * ctxT[(k + 0) * 64 + b];
        a1 += wv.y * ctxT[(k + 1) * 64 + b];
        a2 += wv.z * ctxT[(k + 2) * 64 + b];
        a3 += wv.w * ctxT[(k + 3) * 64 + b];
    }
    co_out[b * H + j] = tanhf(b_oc[j] + ((a0 + a1) + (a2 + a3)));
}

// ---------------------------------------------------------------------------
// K7: logits, no-LDS no-barrier fp16 MFMA (unchanged).
// ---------------------------------------------------------------------------
__global__ __launch_bounds__(256) void k_logits_v3(const float* __restrict__ co,
                                                   const float* __restrict__ W_out,
                                                   const float* __restrict__ b_out,
                                                   float* __restrict__ logits) {
    const int tid  = threadIdx.x;
    const int lane = tid & 63;
    const int w    = tid >> 6;
    const int fr   = lane & 15;
    const int kb   = (lane >> 4) * 8;
    const int j    = blockIdx.x * 64 + w * 16 + fr;

    f32x4 acc[4];
    #pragma unroll
    for (int mf = 0; mf < 4; ++mf) acc[mf] = (f32x4){0.f, 0.f, 0.f, 0.f};

    const float* Arow = &co[(size_t)fr * H + kb];
    const float* Brow = &W_out[(size_t)j * H + kb];

    for (int k0 = 0; k0 < H; k0 += 32) {
        float4 b0 = *reinterpret_cast<const float4*>(Brow + k0);
        float4 b1 = *reinterpret_cast<const float4*>(Brow + k0 + 4);
        half8v bh = cvt8(b0, b1);
        #pragma unroll
        for (int mf = 0; mf < 4; ++mf) {
            const float* ap = Arow + (size_t)mf * 16 * H + k0;
            float4 a0 = *reinterpret_cast<const float4*>(ap);
            float4 a1 = *reinterpret_cast<const float4*>(ap + 4);
            half8v ah = cvt8(a0, a1);
            acc[mf] = __builtin_amdgcn_mfma_f32_16x16x32_f16(ah, bh, acc[mf], 0, 0, 0);
        }
    }
    float bo = b_out[j];
    #pragma unroll
    for (int mf = 0; mf < 4; ++mf) {
        int mbase = mf * 16 + (lane >> 4) * 4;
        #pragma unroll
        for (int r = 0; r < 4; ++r)
            logits[(size_t)(mbase + r) * V + j] = acc[mf][r] + bo;
    }
}

// ---------------------------------------------------------------------------
// K8a: per-(b, chunk) partial max & expsum. grid (8 chunks, 64 b), 256 thr.
// ---------------------------------------------------------------------------
__global__ __launch_bounds__(256) void k_lsm_part(const float* __restrict__ logits,
                                                  float* __restrict__ pmax,
                                                  float* __restrict__ psum) {
    int chunk = blockIdx.x, b = blockIdx.y;
    int tid = threadIdx.x;
    const float* row = &logits[(size_t)b * V + chunk * 4000];
    float v[16];
    float m = -1e30f;
    #pragma unroll
    for (int t = 0; t < 16; ++t) {
        int i = t * 256 + tid;
        v[t] = (i < 4000) ? row[i] : -1e30f;
        m = fmaxf(m, v[t]);
    }
    #pragma unroll
    for (int s = 1; s < 64; s <<= 1) m = fmaxf(m, __shfl_xor(m, s));
    __shared__ float redm[4];
    if ((tid & 63) == 0) redm[tid >> 6] = m;
    __syncthreads();
    m = fmaxf(fmaxf(redm[0], redm[1]), fmaxf(redm[2], redm[3]));
    float s = 0.f;
    #pragma unroll
    for (int t = 0; t < 16; ++t) s += __expf(v[t] - m);
    #pragma unroll
    for (int sh = 1; sh < 64; sh <<= 1) s += __shfl_xor(s, sh);
    __shared__ float reds[4];
    if ((tid & 63) == 0) reds[tid >> 6] = s;
    __syncthreads();
    if (tid == 0) {
        pmax[chunk * 64 + b] = m;
        psum[chunk * 64 + b] = reds[0] + reds[1] + reds[2] + reds[3];
    }
}

// K8b: out = logits - lse[b], lse computed inline from the 8 partials.
__global__ __launch_bounds__(256) void k_lsm_write(const float* __restrict__ logits,
                                                   const float* __restrict__ pmax,
                                                   const float* __restrict__ psum,
                                                   float* __restrict__ out) {
    size_t i4 = ((size_t)blockIdx.x * 256 + threadIdx.x) * 4;
    int b = (int)(i4 / V);
    float m = -1e30f;
    #pragma unroll
    for (int c = 0; c < 8; ++c) m = fmaxf(m, pmax[c * 64 + b]);
    float s = 0.f;
    #pragma unroll
    for (int c = 0; c < 8; ++c) s += psum[c * 64 + b] * __expf(pmax[c * 64 + b] - m);
    float l = m + __logf(s);
    float4 x = *reinterpret_cast<const float4*>(&logits[i4]);
    x.x -= l; x.y -= l; x.z -= l; x.w -= l;
    *reinterpret_cast<float4*>(&out[i4]) = x;
}

// ---------------------------------------------------------------------------
extern "C" void kernel_launch(void* const* d_in, const int* in_sizes, int n_in,
                              void* d_out, int out_size, void* d_ws, size_t ws_size,
                              hipStream_t stream) {
    const int*   inp    = (const int*)  d_in[0];
    const float* loc    = (const float*)d_in[1];
    const float* hprev  = (const float*)d_in[2];
    const float* cprev  = (const float*)d_in[3];
    const float* enc    = (const float*)d_in[4];
    const float* emb    = (const float*)d_in[5];
    const float* W_ih   = (const float*)d_in[6];
    const float* W_hh   = (const float*)d_in[7];
    const float* b_ih   = (const float*)d_in[8];
    const float* b_hh   = (const float*)d_in[9];
    const float* W_attn = (const float*)d_in[10];
    const float* b_attn = (const float*)d_in[11];
    const float* beta   = (const float*)d_in[12];
    const float* W_oc   = (const float*)d_in[13];
    const float* b_oc   = (const float*)d_in[14];
    const float* W_out  = (const float*)d_in[15];
    const float* b_out  = (const float*)d_in[16];

    float* out = (float*)d_out;
    float* out_co = out + (size_t)B * V;
    float* out_h  = out_co + B * H;
    float* out_c  = out_h  + B * H;

    float* ws = (float*)d_ws;
    float* xprev_rm = ws;                                //    81920
    float* hnewT   = xprev_rm + 1280 * 64;               //    32768
    float* hW      = hnewT  + H * 64;                    //    32768
    float* pe      = hW     + H * 64;                    //  4*65536
    float* attnw   = pe     + 4 * M_TOT;                 //    65536
    float* ctxp    = attnw  + M_TOT;                     //  1048576
    float* ctxT    = ctxp   + 32 * 64 * H;               //    32768
    float* logits  = ctxT   + H * 64;                    //  2048000
    float* pmax    = logits + (size_t)B * V;             //      512
    float* psum    = pmax   + 512;                       //      512
    unsigned short* WfB = (unsigned short*)(psum + 512); //   262144 u16

    k_prep  <<<448, 256, 0, stream>>>(W_attn, WfB, inp, loc, hprev, emb, xprev_rm);
    k_lstm_f<<<32, 256, 0, stream>>>(xprev_rm, W_ih, W_hh, b_ih, b_hh, cprev,
                                     out_h, out_c, hnewT);
    k_hw    <<<128, 256, 0, stream>>>(W_attn, b_attn, hnewT, hW);
    k_energy_v15<<<2048, 256, 0, stream>>>(enc, WfB, hW, beta, pe);
    k_softmax_l<<<64, 256, 0, stream>>>(pe, attnw);
    k_ctx_part <<<dim3(32, 64), 128, 0, stream>>>(attnw, enc, ctxp);
    k_ctx_reduce<<<128, 256, 0, stream>>>(ctxp, ctxT);
    k_co    <<<128, 256, 0, stream>>>(W_oc, b_oc, hnewT, ctxT, out_co);
    k_logits_v3<<<500, 256, 0, stream>>>(out_co, W_out, b_out, logits);
    k_lsm_part<<<dim3(8, 64), 256, 0, stream>>>(logits, pmax, psum);
    k_lsm_write<<<2000, 256, 0, stream>>>(logits, pmax, psum, out);
}

// Round 23
// 253.908 us; speedup vs baseline: 1.0385x; 1.0354x over previous
//
#include <hip/hip_runtime.h>
#include <hip/hip_bf16.h>
#include <cstddef>

// Problem dims
#define H   512
#define E   256
#define V   32000
#define L   1024
#define B   64
#define KX  768      // E + H
#define M_TOT 65536  // L*B

typedef __attribute__((ext_vector_type(8))) _Float16 half8v;
typedef __attribute__((ext_vector_type(4))) float f32x4;

__device__ __forceinline__ half8v cvt8(float4 x0, float4 x1) {
    union { half8v v; _Float16 u[8]; } hv;
    hv.u[0] = (_Float16)x0.x; hv.u[1] = (_Float16)x0.y;
    hv.u[2] = (_Float16)x0.z; hv.u[3] = (_Float16)x0.w;
    hv.u[4] = (_Float16)x1.x; hv.u[5] = (_Float16)x1.y;
    hv.u[6] = (_Float16)x1.z; hv.u[7] = (_Float16)x1.w;
    return hv.v;
}

// async global->LDS, 16B per lane; LDS dst = wave-uniform base + lane*16.
// Global SOURCE is per-lane -> encodes the layout permutation (HK s09).
__device__ __forceinline__ void glds16(const void* g, void* l) {
    __builtin_amdgcn_global_load_lds(
        (const __attribute__((address_space(1))) void*)g,
        (__attribute__((address_space(3))) void*)l, 16, 0, 0);
}

// ---------------------------------------------------------------------------
// K-prep: blocks 0..127 -> W_attn[:,H:] into fragment-ordered fp16 WfB;
//         blocks 128..447 -> build xprevT.
// WfB chunk u = ((jt*16+kt)*8 + f)*64 + lane, f = wn*4+nf:
//   j = jt*128 + wn*64 + nf*16 + (lane&15), col = kt*32 + (lane>>4)*8.
// In-kernel B glds is then fully LINEAR; fragment reads contiguous per lane.
// ---------------------------------------------------------------------------
__global__ __launch_bounds__(256) void k_prep(const float* __restrict__ W_attn,
                                              unsigned short* __restrict__ WfB,
                                              const int* __restrict__ inp,
                                              const float* __restrict__ loc,
                                              const float* __restrict__ hprev,
                                              const float* __restrict__ emb,
                                              float* __restrict__ xprevT) {
    if (blockIdx.x < 128) {
        int u = blockIdx.x * 256 + threadIdx.x;   // 0..32767 chunks
        int lane = u & 63;
        int rest = u >> 6;                        // (jt*16+kt)*8 + f
        int f = rest & 7;
        int kt = (rest >> 3) & 15;
        int jt = rest >> 7;
        int wn = f >> 2, nf = f & 3;
        int j = jt * 128 + wn * 64 + nf * 16 + (lane & 15);
        int col = kt * 32 + (lane >> 4) * 8;
        const float* src = &W_attn[(size_t)j * (2 * H) + H + col];
        float4 x0 = *reinterpret_cast<const float4*>(src);
        float4 x1 = *reinterpret_cast<const float4*>(src + 4);
        *reinterpret_cast<half8v*>(&WfB[(size_t)u * 8]) = cvt8(x0, x1);
    } else {
        int gid = (blockIdx.x - 128) * 256 + threadIdx.x;  // 0..81919
        int k = gid >> 6, b = gid & 63;
        float v;
        if (k < 256)      v = emb[(size_t)inp[b] * E + k];
        else if (k < 768) v = loc[b * H + (k - 256)];
        else              v = hprev[b * H + (k - 768)];
        xprevT[gid] = v;
    }
}

// ---------------------------------------------------------------------------
// K1: LSTM cell (fp32)
// ---------------------------------------------------------------------------
__global__ __launch_bounds__(256) void k_lstm(const float* __restrict__ W_ih,
                                              const float* __restrict__ W_hh,
                                              const float* __restrict__ b_ih,
                                              const float* __restrict__ b_hh,
                                              const float* __restrict__ xprevT,
                                              const float* __restrict__ cprev,
                                              float* __restrict__ h_out,
                                              float* __restrict__ c_out,
                                              float* __restrict__ hnewT) {
    int u = blockIdx.x;
    int w = threadIdx.x >> 6;
    int b = threadIdx.x & 63;
    int j = w * 512 + u;
    float a0 = 0.f, a1 = 0.f, a2 = 0.f, a3 = 0.f;
    const float* Wr = &W_ih[(size_t)j * KX];
    for (int k = 0; k < KX; k += 4) {
        float4 wv = *reinterpret_cast<const float4*>(&Wr[k]);
        a0 += wv.x * xprevT[(k + 0) * 64 + b];
        a1 += wv.y * xprevT[(k + 1) * 64 + b];
        a2 += wv.z * xprevT[(k + 2) * 64 + b];
        a3 += wv.w * xprevT[(k + 3) * 64 + b];
    }
    const float* Wr2 = &W_hh[(size_t)j * H];
    const float* hT = &xprevT[KX * 64];
    for (int k = 0; k < H; k += 4) {
        float4 wv = *reinterpret_cast<const float4*>(&Wr2[k]);
        a0 += wv.x * hT[(k + 0) * 64 + b];
        a1 += wv.y * hT[(k + 1) * 64 + b];
        a2 += wv.z * hT[(k + 2) * 64 + b];
        a3 += wv.w * hT[(k + 3) * 64 + b];
    }
    float acc = b_ih[j] + b_hh[j] + ((a0 + a1) + (a2 + a3));
    __shared__ float gs[4][64];
    gs[w][b] = acc;
    __syncthreads();
    if (threadIdx.x < 64) {
        float ig = 1.f / (1.f + __expf(-gs[0][b]));
        float fg = 1.f / (1.f + __expf(-gs[1][b]));
        float gg = tanhf(gs[2][b]);
        float og = 1.f / (1.f + __expf(-gs[3][b]));
        float c = fg * cprev[b * H + u] + ig * gg;
        float h = og * tanhf(c);
        c_out[b * H + u] = c;
        h_out[b * H + u] = h;
        hnewT[u * 64 + b] = h;
    }
}

// ---------------------------------------------------------------------------
// K2: hW_jb[j][b] = b_attn[j] + sum_k h[b][k] * W_attn[j][k]
// ---------------------------------------------------------------------------
__global__ __launch_bounds__(256) void k_hw(const float* __restrict__ W_attn,
                                            const float* __restrict__ b_attn,
                                            const float* __restrict__ hT,
                                            float* __restrict__ hW_jb) {
    int j = blockIdx.x * 4 + (threadIdx.x >> 6);
    int b = threadIdx.x & 63;
    float a0 = 0.f, a1 = 0.f, a2 = 0.f, a3 = 0.f;
    const float* Wr = &W_attn[(size_t)j * (2 * H)];
    for (int k = 0; k < H; k += 4) {
        float4 wv = *reinterpret_cast<const float4*>(&Wr[k]);
        a0 += wv.x * hT[(k + 0) * 64 + b];
        a1 += wv.y * hT[(k + 1) * 64 + b];
        a2 += wv.z * hT[(k + 2) * 64 + b];
        a3 += wv.w * hT[(k + 3) * 64 + b];
    }
    hW_jb[j * 64 + b] = b_attn[j] + ((a0 + a1) + (a2 + a3));
}

// ---------------------------------------------------------------------------
// K3: energy GEMM v12: BK=32, 2 barriers/phase, glds-direct for BOTH operands.
// A staged as RAW fp32 from row-major enc: chunk pos p of row r holds source
// chunk p^(r&7) (same 128B row segment -> coalesced); fragment reads hit 8
// distinct slots per 8-lane group -> conflict-free.  fp32->fp16 at frag read.
// B from fragment-ordered fp16 WfB (linear glds).  XCD swizzle kept.
// Output: partial_e[jt][m].
// ---------------------------------------------------------------------------
__global__ __launch_bounds__(256, 4) void k_energy_v12(
        const float* __restrict__ enc,
        const unsigned short* __restrict__ WfB,
        const float* __restrict__ hW,
        const float* __restrict__ beta,
        float* __restrict__ partial_e) {
    __shared__ float Af[4096];            // 1024 chunks * 4 floats = 16 KB
    __shared__ unsigned short Bh2[4096];  //  512 chunks * 8 halves = 8 KB
    __shared__ float red[2][128];

    const int tid  = threadIdx.x;
    const int lane = tid & 63;
    const int w    = tid >> 6;
    const int wm = w >> 1;
    const int wn = w & 1;
    // XCD-aware swizzle (bijective: 2048 = 8 * 256)
    const int bid = blockIdx.x;
    const int xcd = bid & 7;
    const int loc = bid >> 3;
    const int mt  = xcd * 64 + (loc >> 2);
    const int jt  = loc & 3;
    const int m0 = mt * 128;
    const int j0 = jt * 128;

    const int fr = lane & 15;
    const int g  = lane >> 4;

    // ---- A glds sources (4 per wave): chunk c = (w*4+i)*64+lane,
    // row = c>>3, pos = lane&7, source chunk = pos^(row&7).
    const float* asrcA[4];
    #pragma unroll
    for (int i = 0; i < 4; ++i) {
        int c0 = (w * 4 + i) * 64 + lane;
        int row = c0 >> 3;
        int sc = (lane & 7) ^ (row & 7);
        asrcA[i] = enc + (size_t)(m0 + row) * H + sc * 4;
    }
    // ---- B glds source base (2 per wave), linear in WfB
    const size_t bbase = (size_t)jt * 16 * 512;   // chunks

    f32x4 acc[4][4];
    #pragma unroll
    for (int i = 0; i < 4; ++i)
        #pragma unroll
        for (int j = 0; j < 4; ++j) acc[i][j] = (f32x4){0.f, 0.f, 0.f, 0.f};

    for (int kt = 0; kt < 16; ++kt) {
        // ---- stage: 4 A-glds (fp32) + 2 B-glds (fp16) per wave
        #pragma unroll
        for (int i = 0; i < 4; ++i)
            glds16(asrcA[i] + kt * 32, &Af[((w * 4 + i) * 64 + lane) * 4]);
        #pragma unroll
        for (int i = 0; i < 2; ++i)
            glds16(WfB + (bbase + (size_t)kt * 512 + (w * 2 + i) * 64 + lane) * 8,
                   &Bh2[((w * 2 + i) * 64 + lane) * 8]);
        __syncthreads();                   // drain DMA -> tile resident
        half8v a_h[4], b_h[4];
        #pragma unroll
        for (int mf = 0; mf < 4; ++mf) {
            int R = wm * 64 + mf * 16 + fr;
            int p0 = (2 * g) ^ (R & 7);
            int p1 = p0 ^ 1;
            float4 f0 = *reinterpret_cast<const float4*>(&Af[(R * 8 + p0) * 4]);
            float4 f1 = *reinterpret_cast<const float4*>(&Af[(R * 8 + p1) * 4]);
            a_h[mf] = cvt8(f0, f1);
        }
        #pragma unroll
        for (int nf = 0; nf < 4; ++nf)
            b_h[nf] = *reinterpret_cast<const half8v*>(
                &Bh2[((wn * 4 + nf) * 64 + lane) * 8]);
        #pragma unroll
        for (int mf = 0; mf < 4; ++mf)
            #pragma unroll
            for (int nf = 0; nf < 4; ++nf)
                acc[mf][nf] = __builtin_amdgcn_mfma_f32_16x16x32_f16(
                    a_h[mf], b_h[nf], acc[mf][nf], 0, 0, 0);
        __syncthreads();                   // protect LDS from next DMA
    }

    // ---- epilogue: psum[mf][r] = sum_j tanh(C + hW)*beta ----
    float psum[4][4];
    #pragma unroll
    for (int i = 0; i < 4; ++i)
        #pragma unroll
        for (int r = 0; r < 4; ++r) psum[i][r] = 0.f;
    #pragma unroll
    for (int nf = 0; nf < 4; ++nf) {
        int jj = j0 + wn * 64 + nf * 16 + (lane & 15);
        float bet = beta[jj];
        #pragma unroll
        for (int mf = 0; mf < 4; ++mf) {
            int b_base = (wm * 64 + mf * 16 + (lane >> 4) * 4) & 63;
            float4 hw4 = *reinterpret_cast<const float4*>(&hW[jj * 64 + b_base]);
            float hwv[4] = {hw4.x, hw4.y, hw4.z, hw4.w};
            #pragma unroll
            for (int r = 0; r < 4; ++r) {
                float e = acc[mf][nf][r] + hwv[r];
                float ex = __expf(2.f * e);
                psum[mf][r] += bet * (1.f - 2.f / (ex + 1.f));
            }
        }
    }
    #pragma unroll
    for (int mf = 0; mf < 4; ++mf)
        #pragma unroll
        for (int r = 0; r < 4; ++r) {
            float v = psum[mf][r];
            v += __shfl_xor(v, 1);
            v += __shfl_xor(v, 2);
            v += __shfl_xor(v, 4);
            v += __shfl_xor(v, 8);
            psum[mf][r] = v;
        }
    __syncthreads();
    if ((lane & 15) == 0) {
        #pragma unroll
        for (int mf = 0; mf < 4; ++mf)
            #pragma unroll
            for (int r = 0; r < 4; ++r)
                red[wn][wm * 64 + mf * 16 + (lane >> 4) * 4 + r] = psum[mf][r];
    }
    __syncthreads();
    if (tid < 128)
        partial_e[(size_t)jt * M_TOT + m0 + tid] = red[0][tid] + red[1][tid];
}

// ---------------------------------------------------------------------------
// K4: softmax over l per b.  e[l] = sum_{nb<4} partial_e[nb][l*64+b]
// ---------------------------------------------------------------------------
__global__ __launch_bounds__(256) void k_softmax_l(const float* __restrict__ partial_e,
                                                   float* __restrict__ attn_w) {
    int b = blockIdx.x;
    int tid = threadIdx.x;
    float el[4];
    float m = -1e30f;
    #pragma unroll
    for (int i = 0; i < 4; ++i) {
        int l = i * 256 + tid;
        float e = 0.f;
        #pragma unroll
        for (int nb = 0; nb < 4; ++nb)
            e += partial_e[(size_t)nb * M_TOT + l * 64 + b];
        el[i] = e;
        m = fmaxf(m, e);
    }
    #pragma unroll
    for (int s = 1; s < 64; s <<= 1) m = fmaxf(m, __shfl_xor(m, s));
    __shared__ float redm[4];
    if ((tid & 63) == 0) redm[tid >> 6] = m;
    __syncthreads();
    m = fmaxf(fmaxf(redm[0], redm[1]), fmaxf(redm[2], redm[3]));
    float s = 0.f;
    #pragma unroll
    for (int i = 0; i < 4; ++i) { el[i] = __expf(el[i] - m); s += el[i]; }
    #pragma unroll
    for (int sh = 1; sh < 64; sh <<= 1) s += __shfl_xor(s, sh);
    __shared__ float reds[4];
    if ((tid & 63) == 0) reds[tid >> 6] = s;
    __syncthreads();
    s = reds[0] + reds[1] + reds[2] + reds[3];
    float inv = 1.f / s;
    #pragma unroll
    for (int i = 0; i < 4; ++i)
        attn_w[(i * 256 + tid) * 64 + b] = el[i] * inv;
}

// ---------------------------------------------------------------------------
// K5: context partials over l chunks. float4, 128 threads.
// ---------------------------------------------------------------------------
__global__ __launch_bounds__(128) void k_ctx_part(const float* __restrict__ attn_w,
                                                  const float* __restrict__ enc,
                                                  float* __restrict__ ctx_part) {
    int chunk = blockIdx.x, b = blockIdx.y;
    int h = threadIdx.x * 4;
    float4 acc = {0.f, 0.f, 0.f, 0.f};
    for (int i = 0; i < 32; ++i) {
        int l = chunk * 32 + i;
        float w = attn_w[l * 64 + b];
        float4 e4 = *reinterpret_cast<const float4*>(
            &enc[((size_t)l * 64 + b) * H + h]);
        acc.x += w * e4.x;
        acc.y += w * e4.y;
        acc.z += w * e4.z;
        acc.w += w * e4.w;
    }
    *reinterpret_cast<float4*>(&ctx_part[((size_t)(chunk * 64 + b)) * H + h]) = acc;
}

__global__ __launch_bounds__(256) void k_ctx_reduce(const float* __restrict__ ctx_part,
                                                    float* __restrict__ ctxT) {
    int gid = blockIdx.x * 256 + threadIdx.x;
    int b = gid >> 9, h = gid & 511;
    float s = 0.f;
    for (int c = 0; c < 32; ++c)
        s += ctx_part[((size_t)(c * 64 + b)) * H + h];
    ctxT[h * 64 + b] = s;
}

// ---------------------------------------------------------------------------
// K6: co[b][j] = tanh([h | ctx] . W_oc[j] + b_oc[j])
// ---------------------------------------------------------------------------
__global__ __launch_bounds__(256) void k_co(const float* __restrict__ W_oc,
                                            const float* __restrict__ b_oc,
                                            const float* __restrict__ hT,
                                            const float* __restrict__ ctxT,
                                            float* __restrict__ co_out) {
    int j = blockIdx.x * 4 + (threadIdx.x >> 6);
    int b = threadIdx.x & 63;
    float a0 = 0.f, a1 = 0.f, a2 = 0.f, a3 = 0.f;
    const float* Wr = &W_oc[(size_t)j * (2 * H)];
    for (int k = 0; k < H; k += 4) {
        float4 wv = *reinterpret_cast<const float4*>(&Wr[k]);
        a0 += wv.x * hT[(k + 0) * 64 + b];
        a1 += wv.y * hT[(k + 1) * 64 + b];
        a2 += wv.z * hT[(k + 2) * 64 + b];
        a3 += wv.w * hT[(k + 3) * 64 + b];
    }
    const float* Wr2 = Wr + H;
    for (int k = 0; k < H; k += 4) {
        float4 wv = *reinterpret_cast<const float4*>(&Wr2[k]);
        a0 += wv.x * ctxT[(k + 0) * 64 + b];
        a1 += wv.y * ctxT[(k + 1) * 64 + b];
        a2 += wv.z * ctxT[(k + 2) * 64 + b];
        a3 += wv.w * ctxT[(k + 3) * 64 + b];
    }
    co_out[b * H + j] = tanhf(b_oc[j] + ((a0 + a1) + (a2 + a3)));
}

// ---------------------------------------------------------------------------
// K7: logits, no-LDS no-barrier fp16 MFMA.
// ---------------------------------------------------------------------------
__global__ __launch_bounds__(256) void k_logits_v3(const float* __restrict__ co,
                                                   const float* __restrict__ W_out,
                                                   const float* __restrict__ b_out,
                                                   float* __restrict__ logits) {
    const int tid  = threadIdx.x;
    const int lane = tid & 63;
    const int w    = tid >> 6;
    const int fr   = lane & 15;
    const int kb   = (lane >> 4) * 8;
    const int j    = blockIdx.x * 64 + w * 16 + fr;

    f32x4 acc[4];
    #pragma unroll
    for (int mf = 0; mf < 4; ++mf) acc[mf] = (f32x4){0.f, 0.f, 0.f, 0.f};

    const float* Arow = &co[(size_t)fr * H + kb];
    const float* Brow = &W_out[(size_t)j * H + kb];

    for (int k0 = 0; k0 < H; k0 += 32) {
        float4 b0 = *reinterpret_cast<const float4*>(Brow + k0);
        float4 b1 = *reinterpret_cast<const float4*>(Brow + k0 + 4);
        half8v bh = cvt8(b0, b1);
        #pragma unroll
        for (int mf = 0; mf < 4; ++mf) {
            const float* ap = Arow + (size_t)mf * 16 * H + k0;
            float4 a0 = *reinterpret_cast<const float4*>(ap);
            float4 a1 = *reinterpret_cast<const float4*>(ap + 4);
            half8v ah = cvt8(a0, a1);
            acc[mf] = __builtin_amdgcn_mfma_f32_16x16x32_f16(ah, bh, acc[mf], 0, 0, 0);
        }
    }
    float bo = b_out[j];
    #pragma unroll
    for (int mf = 0; mf < 4; ++mf) {
        int mbase = mf * 16 + (lane >> 4) * 4;
        #pragma unroll
        for (int r = 0; r < 4; ++r)
            logits[(size_t)(mbase + r) * V + j] = acc[mf][r] + bo;
    }
}

// ---------------------------------------------------------------------------
// K8a: per-(b, chunk) partial max & expsum. grid (8 chunks, 64 b), 256 thr.
// ---------------------------------------------------------------------------
__global__ __launch_bounds__(256) void k_lsm_part(const float* __restrict__ logits,
                                                  float* __restrict__ pmax,
                                                  float* __restrict__ psum) {
    int chunk = blockIdx.x, b = blockIdx.y;
    int tid = threadIdx.x;
    const float* row = &logits[(size_t)b * V + chunk * 4000];
    float v[16];
    float m = -1e30f;
    #pragma unroll
    for (int t = 0; t < 16; ++t) {
        int i = t * 256 + tid;
        v[t] = (i < 4000) ? row[i] : -1e30f;
        m = fmaxf(m, v[t]);
    }
    #pragma unroll
    for (int s = 1; s < 64; s <<= 1) m = fmaxf(m, __shfl_xor(m, s));
    __shared__ float redm[4];
    if ((tid & 63) == 0) redm[tid >> 6] = m;
    __syncthreads();
    m = fmaxf(fmaxf(redm[0], redm[1]), fmaxf(redm[2], redm[3]));
    float s = 0.f;
    #pragma unroll
    for (int t = 0; t < 16; ++t) s += __expf(v[t] - m);
    #pragma unroll
    for (int sh = 1; sh < 64; sh <<= 1) s += __shfl_xor(s, sh);
    __shared__ float reds[4];
    if ((tid & 63) == 0) reds[tid >> 6] = s;
    __syncthreads();
    if (tid == 0) {
        pmax[chunk * 64 + b] = m;
        psum[chunk * 64 + b] = reds[0] + reds[1] + reds[2] + reds[3];
    }
}

// K8b: out = logits - lse[b], lse computed inline from the 8 partials
// (16 loads + 8 exp per thread; V % 4 == 0 so a float4 never straddles b).
__global__ __launch_bounds__(256) void k_lsm_write(const float* __restrict__ logits,
                                                   const float* __restrict__ pmax,
                                                   const float* __restrict__ psum,
                                                   float* __restrict__ out) {
    size_t i4 = ((size_t)blockIdx.x * 256 + threadIdx.x) * 4;
    int b = (int)(i4 / V);
    float m = -1e30f;
    #pragma unroll
    for (int c = 0; c < 8; ++c) m = fmaxf(m, pmax[c * 64 + b]);
    float s = 0.f;
    #pragma unroll
    for (int c = 0; c < 8; ++c) s += psum[c * 64 + b] * __expf(pmax[c * 64 + b] - m);
    float l = m + __logf(s);
    float4 x = *reinterpret_cast<const float4*>(&logits[i4]);
    x.x -= l; x.y -= l; x.z -= l; x.w -= l;
    *reinterpret_cast<float4*>(&out[i4]) = x;
}

// ---------------------------------------------------------------------------
extern "C" void kernel_launch(void* const* d_in, const int* in_sizes, int n_in,
                              void* d_out, int out_size, void* d_ws, size_t ws_size,
                              hipStream_t stream) {
    const int*   inp    = (const int*)  d_in[0];
    const float* loc    = (const float*)d_in[1];
    const float* hprev  = (const float*)d_in[2];
    const float* cprev  = (const float*)d_in[3];
    const float* enc    = (const float*)d_in[4];
    const float* emb    = (const float*)d_in[5];
    const float* W_ih   = (const float*)d_in[6];
    const float* W_hh   = (const float*)d_in[7];
    const float* b_ih   = (const float*)d_in[8];
    const float* b_hh   = (const float*)d_in[9];
    const float* W_attn = (const float*)d_in[10];
    const float* b_attn = (const float*)d_in[11];
    const float* beta   = (const float*)d_in[12];
    const float* W_oc   = (const float*)d_in[13];
    const float* b_oc   = (const float*)d_in[14];
    const float* W_out  = (const float*)d_in[15];
    const float* b_out  = (const float*)d_in[16];

    float* out = (float*)d_out;
    float* out_co = out + (size_t)B * V;
    float* out_h  = out_co + B * H;
    float* out_c  = out_h  + B * H;

    float* ws = (float*)d_ws;
    float* xprevT = ws;                                  //    81920
    float* hnewT  = xprevT + 1280 * 64;                  //    32768
    float* hW     = hnewT  + H * 64;                     //    32768
    float* pe     = hW     + H * 64;                     //  4*65536
    float* attnw  = pe     + 4 * M_TOT;                  //    65536
    float* ctxp   = attnw  + M_TOT;                      //  1048576
    float* ctxT   = ctxp   + 32 * 64 * H;                //    32768
    float* logits = ctxT   + H * 64;                     //  2048000
    float* pmax   = logits + (size_t)B * V;              //      512
    float* psum   = pmax   + 512;                        //      512
    float* lse    = psum   + 512;                        //       64
    unsigned short* WfB = (unsigned short*)(lse + 64);   //   262144 u16

    k_prep  <<<448, 256, 0, stream>>>(W_attn, WfB, inp, loc, hprev, emb, xprevT);
    k_lstm  <<<512, 256, 0, stream>>>(W_ih, W_hh, b_ih, b_hh, xprevT, cprev,
                                      out_h, out_c, hnewT);
    k_hw    <<<128, 256, 0, stream>>>(W_attn, b_attn, hnewT, hW);
    k_energy_v12<<<2048, 256, 0, stream>>>(enc, WfB, hW, beta, pe);
    k_softmax_l<<<64, 256, 0, stream>>>(pe, attnw);
    k_ctx_part <<<dim3(32, 64), 128, 0, stream>>>(attnw, enc, ctxp);
    k_ctx_reduce<<<128, 256, 0, stream>>>(ctxp, ctxT);
    k_co    <<<128, 256, 0, stream>>>(W_oc, b_oc, hnewT, ctxT, out_co);
    k_logits_v3<<<500, 256, 0, stream>>>(out_co, W_out, b_out, logits);
    k_lsm_part<<<dim3(8, 64), 256, 0, stream>>>(logits, pmax, psum);
    k_lsm_write<<<2000, 256, 0, stream>>>(logits, pmax, psum, out);
}